// Round 16
// baseline (557.125 us; speedup 1.0000x reference)
//
#include <hip/hip_runtime.h>
#include <hip/hip_bf16.h>
#include <math.h>

#define L_CNT 20000
#define U_CNT 2048
#define M_CNT 3
#define D_CNT 256
#define KTOT  768
#define T_CNT 5
#define K_OUT 8
#define KC    16
#define LP    20096              // 157*128, padded fp16 row stride
#define LROWS (L_CNT*M_CNT)      // 60000
#define UROWS (U_CNT*M_CNT)      // 6144
#define CHUNKS 313               // ceil(20000/64); chunk 312 has 32 valid elems
#define CPAD   320

typedef unsigned short ushort_t;
typedef unsigned int uint_t;
typedef __attribute__((ext_vector_type(8))) short bf16x8;
typedef __attribute__((ext_vector_type(4))) float f32x4;

// -------- helpers --------
__device__ inline double dshfl_xor(double v, int m){
    long long x = __double_as_longlong(v);
    int lo = (int)(x & 0xffffffffLL);
    int hi = (int)(((unsigned long long)x) >> 32);
    lo = __shfl_xor(lo, m, 64);
    hi = __shfl_xor(hi, m, 64);
    return __longlong_as_double(((long long)hi << 32) | (long long)(unsigned int)lo);
}
__device__ inline unsigned short f2bf(float f){
    unsigned int u = __float_as_uint(f);
    u = (u + 0x7fffu + ((u >> 16) & 1u)) >> 16;
    return (unsigned short)u;
}
__device__ __forceinline__ void gload16(const void* g, void* l){
    __builtin_amdgcn_global_load_lds(
        (const __attribute__((address_space(1))) unsigned int*)g,
        (__attribute__((address_space(3))) unsigned int*)l, 16, 0, 0);
}
__device__ __forceinline__ float h2f(ushort_t h){
    _Float16 x; __builtin_memcpy(&x, &h, 2); return (float)x;
}
// f32 -> fp16 bits (RNE)
__device__ __forceinline__ ushort_t f2h(float f){
    _Float16 hv = (_Float16)f;
    ushort_t b; __builtin_memcpy(&b, &hv, 2);
    return b;
}
// f32 -> fp16 bits -> sortable u16 key (unsigned compare == float compare)
__device__ __forceinline__ ushort_t f2key(float f){
    ushort_t b = f2h(f);
    ushort_t mask = (ushort_t)(0x8000u | (((short)b >> 15) & 0x7FFF));
    return (ushort_t)(b ^ mask);
}
__device__ __forceinline__ ushort_t get16(const uint4& v, int e){
    uint_t w = (e < 2) ? v.x : (e < 4) ? v.y : (e < 6) ? v.z : v.w;
    return (ushort_t)((e & 1) ? (w >> 16) : (w & 0xFFFFu));
}
// fixed-order combine: MUST be bit-identical everywhere it is evaluated
__device__ __forceinline__ float comb3(float w0, float w1, float w2, float a, float b, float c){
    return fmaf(w2, c, fmaf(w1, b, w0*a));
}
// suffix-scan a 256-bucket histogram, find bucket where count(>=) crosses kc
__device__ __forceinline__ void radix_find(uint_t hist[4][256], uint_t* h1, uint_t* h2,
    int tid, uint_t addBase, uint_t kc, uint_t* shB, uint_t* shAbove)
{
    h1[tid] = hist[0][tid]+hist[1][tid]+hist[2][tid]+hist[3][tid];
    uint_t* src = h1; uint_t* dst = h2;
    for (int st=1; st<256; st<<=1){
        __syncthreads();
        dst[tid] = src[tid] + ((tid+st < 256) ? src[tid+st] : 0u);
        uint_t* tt = src; src = dst; dst = tt;
    }
    __syncthreads();
    uint_t ge = src[tid] + addBase;
    uint_t gt = ((tid < 255) ? src[tid+1] : 0u) + addBase;
    if (ge >= kc && gt < kc){ *shB = (uint_t)tid; *shAbove = gt; }
    __syncthreads();
}

// -------- K1: f64 inv-norms + normalized bf16 copies + softmax weights (fused) --------
__global__ __launch_bounds__(256) void prep_kernel(const float* __restrict__ lab,
    const float* __restrict__ unl, const float* __restrict__ logits,
    double* __restrict__ invL64, double* __restrict__ invU64,
    ushort_t* __restrict__ labN, ushort_t* __restrict__ unlN,
    float* __restrict__ w32, double* __restrict__ w64){
    // block 0 additionally computes the softmax weights (tiny)
    if (blockIdx.x == 0 && threadIdx.x < T_CNT){
        int t = threadIdx.x;
        float a = logits[t*M_CNT+0], b = logits[t*M_CNT+1], c = logits[t*M_CNT+2];
        float mx = fmaxf(a, fmaxf(b, c));
        float e0 = expf(a-mx), e1 = expf(b-mx), e2 = expf(c-mx);
        float s = e0+e1+e2;
        w32[t*M_CNT+0] = e0/s; w32[t*M_CNT+1] = e1/s; w32[t*M_CNT+2] = e2/s;
        double da=(double)a, db=(double)b, dc=(double)c;
        double dmx = fmax(da, fmax(db, dc));
        double f0 = exp(da-dmx), f1 = exp(db-dmx), f2 = exp(dc-dmx);
        double ds = f0+f1+f2;
        w64[t*M_CNT+0] = f0/ds; w64[t*M_CNT+1] = f1/ds; w64[t*M_CNT+2] = f2/ds;
    }
    const int NROW = LROWS + UROWS;
    int row = blockIdx.x*4 + (threadIdx.x >> 6);
    int lane = threadIdx.x & 63;
    if (row >= NROW) return;
    bool isLab = row < LROWS;
    const float* p = isLab ? (lab + (size_t)row*D_CNT) : (unl + (size_t)(row-LROWS)*D_CNT);
    float4 a = ((const float4*)p)[lane];
    double sS = (double)a.x*a.x + (double)a.y*a.y + (double)a.z*a.z + (double)a.w*a.w;
#pragma unroll
    for (int m=1;m<64;m<<=1) sS += dshfl_xor(sS, m);
    double inv = 1.0/(sqrt(sS) + 1e-8);
    if (lane == 0){
        if (isLab) invL64[row] = inv;
        else invU64[row-LROWS] = inv;
    }
    float sc = (float)inv;
    ushort4 o;
    o.x = f2bf(a.x*sc); o.y = f2bf(a.y*sc); o.z = f2bf(a.z*sc); o.w = f2bf(a.w*sc);
    ushort_t* dst = isLab ? (labN + (size_t)row*D_CNT) : (unlN + (size_t)(row-LROWS)*D_CNT);
    *(ushort4*)&dst[lane*4] = o;
}

// -------- K2: bf16 MFMA modality GEMM -> 3 fp16 planes + fused chunk maxima --------
// grid (16, 157); block 256 (4 waves 2x2, wave tile 64x64). One dispatch for all u.
// R8-proven structure. Chunk maxima via monotone-max: fmaxf in f32, ONE f2key at the
// end (max over keys == key of max, both transforms monotone) -> identical bits.
__global__ __launch_bounds__(256, 2) void sim_kernel(
    const ushort_t* __restrict__ labN, const ushort_t* __restrict__ unlN,
    const float* __restrict__ w32, ushort_t* __restrict__ slabp,
    ushort_t* __restrict__ chunkMax)
{
    __shared__ ushort_t sA[128][64];   // 16 KB
    __shared__ ushort_t sB[128][64];   // 16 KB
    __shared__ float    sT[64][132];   // 33.8 KB (half-tile transpose, 2 phases)

    const int tid  = threadIdx.x;
    const int lane = tid & 63;
    const int w    = tid >> 6;
    const int wu = w >> 1, wl = w & 1;
    const int fr = lane & 15, fg = lane >> 4;

    const int uB = blockIdx.x * 128;
    const int l0 = blockIdx.y * 128;

    // staging: pre-swizzled global source, linear LDS dest (wave-uniform base)
    const int sr   = lane >> 3;                  // 0..7 sub-row within 8-row group
    const int scol = ((lane & 7) ^ sr) * 8;      // swizzled source col (elements)
    const ushort_t* pA[4]; const ushort_t* pB[4];
    ushort_t* dA[4]; ushort_t* dB[4];
#pragma unroll
    for (int g=0; g<4; g++){
        int ar = uB + g*32 + w*8 + sr;
        pA[g] = unlN + (size_t)ar*KTOT + scol;
        dA[g] = &sA[g*32 + w*8][0];
        int br = l0 + g*32 + w*8 + sr; if (br > L_CNT-1) br = L_CNT-1;
        pB[g] = labN + (size_t)br*KTOT + scol;
        dB[g] = &sB[g*32 + w*8][0];
    }

    // fragment read byte-offsets (matching XOR swizzle: slot ^= row&7)
    int aoff[4][2], boff[4][2];
#pragma unroll
    for (int i=0;i<4;i++)
#pragma unroll
        for (int ks=0;ks<2;ks++){
            int sw = ((ks*4 + fg) ^ (fr & 7)) * 16;
            aoff[i][ks] = (wu*64 + i*16 + fr)*128 + sw;
            boff[i][ks] = (wl*64 + i*16 + fr)*128 + sw;
        }

    // fp16-bit carry of this thread's 64 epilogue elements, for m=0 and m=1
    uint4 hA[2][4], hB[2][4];

#pragma unroll
    for (int m=0; m<M_CNT; m++){
        f32x4 acc[4][4];
#pragma unroll
        for (int i=0;i<4;i++)
#pragma unroll
            for (int j=0;j<4;j++) acc[i][j] = (f32x4){0.f,0.f,0.f,0.f};

#pragma unroll
        for (int kb=0; kb<4; kb++){
            const int koff = (m*4 + kb) * 64;
            __syncthreads();
#pragma unroll
            for (int g=0; g<4; g++){
                gload16(pA[g] + koff, dA[g]);
                gload16(pB[g] + koff, dB[g]);
            }
            __syncthreads();
#pragma unroll
            for (int ks=0; ks<2; ks++){
                bf16x8 af[4], bf[4];
#pragma unroll
                for (int i=0;i<4;i++) af[i] = *(const bf16x8*)((const char*)sA + aoff[i][ks]);
#pragma unroll
                for (int j=0;j<4;j++) bf[j] = *(const bf16x8*)((const char*)sB + boff[j][ks]);
#pragma unroll
                for (int i=0;i<4;i++)
#pragma unroll
                    for (int j=0;j<4;j++)
                        acc[i][j] = __builtin_amdgcn_mfma_f32_16x16x32_bf16(af[i], bf[j], acc[i][j], 0, 0, 0);
            }
        }

        // weights only needed for the fused maxima at m==2
        float wl5[T_CNT][3];
        if (m == 2){
#pragma unroll
            for (int t=0;t<T_CNT;t++)
#pragma unroll
                for (int j=0;j<3;j++) wl5[t][j] = w32[t*3+j];
        }

        // epilogue modality m: two-phase transpose (u-halves) through sT[64][132]
#pragma unroll
        for (int half=0; half<2; half++){
            __syncthreads();          // sT free (prev phase's reads done)
            if (wu == half){
#pragma unroll
                for (int i=0;i<4;i++)
#pragma unroll
                    for (int j=0;j<4;j++)
#pragma unroll
                        for (int r=0;r<4;r++)
                            sT[i*16 + fg*4 + r][wl*64 + j*16 + fr] = acc[i][j][r];
            }
            __syncthreads();
            // store 64 rows x 128 cols as fp16 (coalesced 16B per thread)
            const int c0 = (tid & 15) * 8;          // 0..120
#pragma unroll
            for (int it=0; it<4; it++){
                int row = it*16 + (tid >> 4);       // 0..63
                ushort_t h[8];
#pragma unroll
                for (int e=0;e<8;e++) h[e] = f2h(sT[row][c0 + e]);
                uint4 hv = *(const uint4*)h;
                size_t base = ((size_t)(uB + half*64 + row)*M_CNT + m)*LP + l0 + c0;
                *(uint4*)&slabp[base] = hv;

                if (m == 0) hA[half][it] = hv;
                else if (m == 1) hB[half][it] = hv;
                else {
                    // fused chunk maxima in FLOAT space (monotone-max), key-convert once
                    float rmf[T_CNT];
#pragma unroll
                    for (int t=0;t<T_CNT;t++) rmf[t] = -INFINITY;
#pragma unroll
                    for (int e=0;e<8;e++){
                        int l = l0 + c0 + e;
                        float a = h2f(get16(hA[half][it], e));
                        float b = h2f(get16(hB[half][it], e));
                        float c = h2f(get16(hv, e));
                        if (l < L_CNT){
#pragma unroll
                            for (int t=0;t<T_CNT;t++)
                                rmf[t] = fmaxf(rmf[t], comb3(wl5[t][0],wl5[t][1],wl5[t][2], a,b,c));
                        }
                    }
#pragma unroll
                    for (int t=0;t<T_CNT;t++){
                        float k = rmf[t];
                        k = fmaxf(k, __shfl_xor(k, 1, 64));
                        k = fmaxf(k, __shfl_xor(k, 2, 64));
                        k = fmaxf(k, __shfl_xor(k, 4, 64));
                        rmf[t] = k;
                    }
                    if ((tid & 7) == 0){
                        int chunkc = (l0 >> 6) + ((tid >> 3) & 1);
                        if (chunkc < CHUNKS){
                            int ug = uB + half*64 + row;
#pragma unroll
                            for (int t=0;t<T_CNT;t++)
                                chunkMax[((size_t)ug*T_CNT + t)*CPAD + chunkc] = f2key(rmf[t]);
                        }
                    }
                }
            }
        }
        __syncthreads();
    }
}

// -------- K3b: exact top-KC per (u,t) via chunk-pruned radix --------
// grid (U_CNT, T_CNT); block 256; ~8 KB LDS -> full occupancy.
__global__ __launch_bounds__(256) void select2_kernel(
    const ushort_t* __restrict__ slabp, const ushort_t* __restrict__ chunkMax,
    const float* __restrict__ w32, int* __restrict__ candIdx)
{
    __shared__ ushort_t mxs[CPAD];
    __shared__ ushort_t cand[CPAD];
    __shared__ uint_t hist[4][256];
    __shared__ uint_t h1[256], h2[256];
    __shared__ uint_t shB, shAbove, shNc, shCtr0, shCtr1;
    __shared__ int bufc[KC];

    const int tid = threadIdx.x, wid = tid >> 6;
    const int u = blockIdx.x, t = blockIdx.y;
    const float w0 = w32[t*3+0], w1 = w32[t*3+1], w2 = w32[t*3+2];
    const ushort_t* s0 = slabp + ((size_t)u*M_CNT + 0)*LP;
    const ushort_t* s1 = slabp + ((size_t)u*M_CNT + 1)*LP;
    const ushort_t* s2 = slabp + ((size_t)u*M_CNT + 2)*LP;
    const ushort_t* cm = chunkMax + ((size_t)u*T_CNT + t)*CPAD;

    for (int i=tid; i<CPAD; i+=256) mxs[i] = (i < CHUNKS) ? cm[i] : (ushort_t)0;
    hist[0][tid]=0; hist[1][tid]=0; hist[2][tid]=0; hist[3][tid]=0;
    if (tid == 0){ shNc = 0; shCtr0 = 0; shCtr1 = 0; }
    __syncthreads();

    // ---- tau = exact 16th-largest chunk max (2-level radix on 313 values) ----
    for (int i=tid; i<CHUNKS; i+=256) atomicAdd(&hist[wid][mxs[i] >> 8], 1u);
    __syncthreads();
    radix_find(hist, h1, h2, tid, 0u, KC, &shB, &shAbove);
    const uint_t MB = shB, mAb = shAbove;
    hist[0][tid]=0; hist[1][tid]=0; hist[2][tid]=0; hist[3][tid]=0;
    __syncthreads();
    for (int i=tid; i<CHUNKS; i+=256){
        uint_t k = mxs[i];
        if ((k >> 8) == MB) atomicAdd(&hist[wid][k & 0xFFu], 1u);
    }
    __syncthreads();
    radix_find(hist, h1, h2, tid, mAb, KC, &shB, &shAbove);
    const uint_t tau = (MB << 8) | shB;
    hist[0][tid]=0; hist[1][tid]=0; hist[2][tid]=0; hist[3][tid]=0;
    __syncthreads();

    // ---- collect candidate chunks ----
    for (int i=tid; i<CHUNKS; i+=256)
        if ((uint_t)mxs[i] >= tau) cand[atomicAdd(&shNc, 1u)] = (ushort_t)i;
    __syncthreads();
    const int NE = (int)shNc * 64;

    // ---- element pass 1: hi-byte histogram over candidate elements ----
    for (int j=tid; j<NE; j+=256){
        int l = (int)cand[j>>6]*64 + (j & 63);
        if (l < L_CNT){
            uint_t k = f2key(comb3(w0,w1,w2, h2f(s0[l]), h2f(s1[l]), h2f(s2[l])));
            atomicAdd(&hist[wid][k >> 8], 1u);
        }
    }
    __syncthreads();
    radix_find(hist, h1, h2, tid, 0u, KC, &shB, &shAbove);
    const uint_t EB = shB, eAb = shAbove;
    hist[0][tid]=0; hist[1][tid]=0; hist[2][tid]=0; hist[3][tid]=0;
    __syncthreads();

    // ---- element pass 2: low-byte within bucket EB ----
    for (int j=tid; j<NE; j+=256){
        int l = (int)cand[j>>6]*64 + (j & 63);
        if (l < L_CNT){
            uint_t k = f2key(comb3(w0,w1,w2, h2f(s0[l]), h2f(s1[l]), h2f(s2[l])));
            if ((k >> 8) == EB) atomicAdd(&hist[wid][k & 0xFFu], 1u);
        }
    }
    __syncthreads();
    radix_find(hist, h1, h2, tid, eAb, KC, &shB, &shAbove);
    const uint_t K16 = (EB << 8) | shB;
    const uint_t tot = shAbove;          // #(key > K16) < KC

    // ---- element pass 3: collect above-set + fill with ties ----
    for (int j=tid; j<NE; j+=256){
        int l = (int)cand[j>>6]*64 + (j & 63);
        if (l < L_CNT){
            uint_t k = f2key(comb3(w0,w1,w2, h2f(s0[l]), h2f(s1[l]), h2f(s2[l])));
            if (k > K16){
                bufc[atomicAdd(&shCtr0, 1u)] = l;
            } else if (k == K16){
                uint_t s = atomicAdd(&shCtr1, 1u) + tot;
                if (s < (uint_t)KC) bufc[s] = l;
            }
        }
    }
    __syncthreads();
    if (tid < KC) candIdx[((size_t)u*T_CNT + t)*KC + tid] = bufc[tid];
}

// -------- K4: fused f64 rescore + sort + trait/index outputs + embedding gather --------
// grid (U_CNT*T_CNT); block 1024 = 16 waves, ONE WAVE PER CANDIDATE (4x the MLP of the
// serial 4-candidate loop). Embedding output via non-temporal stores.
__global__ __launch_bounds__(1024) void rfg_kernel(
    const float* __restrict__ lab, const float* __restrict__ unl,
    const double* __restrict__ w64, const double* __restrict__ invL64,
    const double* __restrict__ invU64, const int* __restrict__ candIdx,
    const float* __restrict__ traits,
    float* __restrict__ outEmb, float* __restrict__ outTraits, float* __restrict__ outIdx)
{
    __shared__ double sval[KC];
    __shared__ int sidx[KC];
    __shared__ int finals[K_OUT];

    const int ut = blockIdx.x;              // u*T + t
    const int t = ut % T_CNT, u = ut / T_CNT;
    const int tid = threadIdx.x;
    const int wv = tid >> 6, lane = tid & 63;   // wv = candidate 0..15

    // rescore candidate wv (numerics identical to R15: ((w*iu)*il)*d, one butterfly)
    {
        int idx = candIdx[(size_t)ut*KC + wv];
        double p = 0.0;
#pragma unroll
        for (int m=0;m<3;m++){
            float4 a = *(const float4*)&unl[(((size_t)u*M_CNT)+m)*D_CNT + lane*4];
            float4 b = *(const float4*)&lab[(((size_t)idx*M_CNT)+m)*D_CNT + lane*4];
            double d = (double)a.x*b.x + (double)a.y*b.y + (double)a.z*b.z + (double)a.w*b.w;
            p += ((w64[t*M_CNT+m] * invU64[u*M_CNT+m]) * invL64[idx*M_CNT+m]) * d;
        }
#pragma unroll
        for (int mm=1;mm<64;mm<<=1) p += dshfl_xor(p, mm);
        if (lane == 0){ sval[wv] = p; sidx[wv] = idx; }
    }
    __syncthreads();

    if (tid == 0){
        double cv[KC]; int ci[KC];
#pragma unroll
        for (int c=0;c<KC;c++){ cv[c] = sval[c]; ci[c] = sidx[c]; }
#pragma unroll
        for (int i=0;i<KC;i++)
#pragma unroll
            for (int j=0;j<KC-1;j++){
                bool sw = (cv[j] < cv[j+1]) || (cv[j] == cv[j+1] && ci[j] > ci[j+1]);
                if (sw){ double tv=cv[j]; cv[j]=cv[j+1]; cv[j+1]=tv; int ti=ci[j]; ci[j]=ci[j+1]; ci[j+1]=ti; }
            }
#pragma unroll
        for (int k=0;k<K_OUT;k++){
            int fi = ci[k];
            finals[k] = fi;
            size_t ob = (size_t)ut*K_OUT + k;
            outTraits[ob] = traits[(size_t)fi*T_CNT + t];
            outIdx[ob] = (float)fi;
        }
    }
    __syncthreads();

    // gather the 8 winning embeddings (rows L2-hot from the rescore reads just above)
    for (int it = tid; it < K_OUT*192; it += 1024){   // 192 float4 per 768-f32 row
        int k = it / 192, o = it % 192;
        int fi = finals[k];
        f32x4 v = ((const f32x4*)(lab + (size_t)fi*(M_CNT*D_CNT)))[o];
        __builtin_nontemporal_store(v, ((f32x4*)(outEmb + ((size_t)ut*K_OUT + k)*(M_CNT*D_CNT))) + o);
    }
}

extern "C" void kernel_launch(void* const* d_in, const int* in_sizes, int n_in,
                              void* d_out, int out_size, void* d_ws, size_t ws_size,
                              hipStream_t stream) {
    const float* lab    = (const float*)d_in[0];   // [20000,3,256]
    const float* traits = (const float*)d_in[1];   // [20000,5]
    const float* unl    = (const float*)d_in[2];   // [2048,3,256]
    const float* logits = (const float*)d_in[3];   // [5,3]

    float* out = (float*)d_out;
    float* outEmb = out;                                           // U*T*K*M*D = 62,914,560 f32
    float* outTr  = out + (size_t)U_CNT*T_CNT*K_OUT*M_CNT*D_CNT;
    float* outIx  = outTr + (size_t)U_CNT*T_CNT*K_OUT;

    char* wsb = (char*)d_ws;
    size_t off = 0;
    auto take = [&](size_t bytes)->void*{
        void* p = wsb + off;
        off = (off + bytes + 255) & ~(size_t)255;
        return p;
    };
    double* invL64 = (double*)take((size_t)LROWS*sizeof(double));
    double* invU64 = (double*)take((size_t)UROWS*sizeof(double));
    float*  w32    = (float*) take(T_CNT*M_CNT*sizeof(float));
    double* w64    = (double*)take(T_CNT*M_CNT*sizeof(double));
    int*    candIdx= (int*)   take((size_t)U_CNT*T_CNT*KC*sizeof(int));
    ushort_t* labN = (ushort_t*)take((size_t)LROWS*D_CNT*sizeof(ushort_t)); // 30.7 MB
    ushort_t* unlN = (ushort_t*)take((size_t)UROWS*D_CNT*sizeof(ushort_t)); // 3.15 MB
    ushort_t* chunkMax = (ushort_t*)take((size_t)U_CNT*T_CNT*CPAD*sizeof(ushort_t)); // 6.55 MB

    // modality-sim slab [u][m][LP] fp16 lives in d_out's embedding region:
    // 2048*3*20096*2 = 246.9 MB <= 251.66 MB. Fully consumed before rfg overwrites it.
    ushort_t* slabV = (ushort_t*)outEmb;

    {
        int nrow = LROWS + UROWS;
        prep_kernel<<<(nrow+3)/4, 256, 0, stream>>>(lab, unl, logits, invL64, invU64, labN, unlN, w32, w64);
    }
    sim_kernel<<<dim3(U_CNT/128, (L_CNT + 127)/128), 256, 0, stream>>>(labN, unlN, w32, slabV, chunkMax);
    select2_kernel<<<dim3(U_CNT, T_CNT), 256, 0, stream>>>(slabV, chunkMax, w32, candIdx);
    rfg_kernel<<<U_CNT*T_CNT, 1024, 0, stream>>>(lab, unl, w64, invL64, invU64, candIdx, traits, outEmb, outTr, outIx);
}

// Round 17
// 399.919 us; speedup vs baseline: 1.3931x; 1.3931x over previous
//
#include <hip/hip_runtime.h>
#include <hip/hip_bf16.h>
#include <math.h>

#define L_CNT 20000
#define U_CNT 2048
#define M_CNT 3
#define D_CNT 256
#define KTOT  768
#define T_CNT 5
#define K_OUT 8
#define KC    16
#define LP    20096              // 157*128, padded fp16 row stride
#define LROWS (L_CNT*M_CNT)      // 60000
#define UROWS (U_CNT*M_CNT)      // 6144
#define CHUNKS 313               // ceil(20000/64); chunk 312 has 32 valid elems
#define CPAD   320

typedef unsigned short ushort_t;
typedef unsigned int uint_t;
typedef __attribute__((ext_vector_type(8))) short bf16x8;
typedef __attribute__((ext_vector_type(4))) float f32x4;

// -------- helpers --------
__device__ inline double dshfl_xor(double v, int m){
    long long x = __double_as_longlong(v);
    int lo = (int)(x & 0xffffffffLL);
    int hi = (int)(((unsigned long long)x) >> 32);
    lo = __shfl_xor(lo, m, 64);
    hi = __shfl_xor(hi, m, 64);
    return __longlong_as_double(((long long)hi << 32) | (long long)(unsigned int)lo);
}
__device__ inline unsigned short f2bf(float f){
    unsigned int u = __float_as_uint(f);
    u = (u + 0x7fffu + ((u >> 16) & 1u)) >> 16;
    return (unsigned short)u;
}
__device__ __forceinline__ void gload16(const void* g, void* l){
    __builtin_amdgcn_global_load_lds(
        (const __attribute__((address_space(1))) unsigned int*)g,
        (__attribute__((address_space(3))) unsigned int*)l, 16, 0, 0);
}
__device__ __forceinline__ float h2f(ushort_t h){
    _Float16 x; __builtin_memcpy(&x, &h, 2); return (float)x;
}
// f32 -> fp16 bits (RNE)
__device__ __forceinline__ ushort_t f2h(float f){
    _Float16 hv = (_Float16)f;
    ushort_t b; __builtin_memcpy(&b, &hv, 2);
    return b;
}
// f32 -> fp16 bits -> sortable u16 key (unsigned compare == float compare)
__device__ __forceinline__ ushort_t f2key(float f){
    ushort_t b = f2h(f);
    ushort_t mask = (ushort_t)(0x8000u | (((short)b >> 15) & 0x7FFF));
    return (ushort_t)(b ^ mask);
}
__device__ __forceinline__ ushort_t get16(const uint4& v, int e){
    uint_t w = (e < 2) ? v.x : (e < 4) ? v.y : (e < 6) ? v.z : v.w;
    return (ushort_t)((e & 1) ? (w >> 16) : (w & 0xFFFFu));
}
// fixed-order combine: MUST be bit-identical everywhere it is evaluated
__device__ __forceinline__ float comb3(float w0, float w1, float w2, float a, float b, float c){
    return fmaf(w2, c, fmaf(w1, b, w0*a));
}
// suffix-scan a 256-bucket histogram, find bucket where count(>=) crosses kc
__device__ __forceinline__ void radix_find(uint_t hist[4][256], uint_t* h1, uint_t* h2,
    int tid, uint_t addBase, uint_t kc, uint_t* shB, uint_t* shAbove)
{
    h1[tid] = hist[0][tid]+hist[1][tid]+hist[2][tid]+hist[3][tid];
    uint_t* src = h1; uint_t* dst = h2;
    for (int st=1; st<256; st<<=1){
        __syncthreads();
        dst[tid] = src[tid] + ((tid+st < 256) ? src[tid+st] : 0u);
        uint_t* tt = src; src = dst; dst = tt;
    }
    __syncthreads();
    uint_t ge = src[tid] + addBase;
    uint_t gt = ((tid < 255) ? src[tid+1] : 0u) + addBase;
    if (ge >= kc && gt < kc){ *shB = (uint_t)tid; *shAbove = gt; }
    __syncthreads();
}

// -------- K1: f64 inv-norms + normalized bf16 copies + softmax weights (fused) --------
__global__ __launch_bounds__(256) void prep_kernel(const float* __restrict__ lab,
    const float* __restrict__ unl, const float* __restrict__ logits,
    double* __restrict__ invL64, double* __restrict__ invU64,
    ushort_t* __restrict__ labN, ushort_t* __restrict__ unlN,
    float* __restrict__ w32, double* __restrict__ w64){
    // block 0 additionally computes the softmax weights (tiny)
    if (blockIdx.x == 0 && threadIdx.x < T_CNT){
        int t = threadIdx.x;
        float a = logits[t*M_CNT+0], b = logits[t*M_CNT+1], c = logits[t*M_CNT+2];
        float mx = fmaxf(a, fmaxf(b, c));
        float e0 = expf(a-mx), e1 = expf(b-mx), e2 = expf(c-mx);
        float s = e0+e1+e2;
        w32[t*M_CNT+0] = e0/s; w32[t*M_CNT+1] = e1/s; w32[t*M_CNT+2] = e2/s;
        double da=(double)a, db=(double)b, dc=(double)c;
        double dmx = fmax(da, fmax(db, dc));
        double f0 = exp(da-dmx), f1 = exp(db-dmx), f2 = exp(dc-dmx);
        double ds = f0+f1+f2;
        w64[t*M_CNT+0] = f0/ds; w64[t*M_CNT+1] = f1/ds; w64[t*M_CNT+2] = f2/ds;
    }
    const int NROW = LROWS + UROWS;
    int row = blockIdx.x*4 + (threadIdx.x >> 6);
    int lane = threadIdx.x & 63;
    if (row >= NROW) return;
    bool isLab = row < LROWS;
    const float* p = isLab ? (lab + (size_t)row*D_CNT) : (unl + (size_t)(row-LROWS)*D_CNT);
    float4 a = ((const float4*)p)[lane];
    double sS = (double)a.x*a.x + (double)a.y*a.y + (double)a.z*a.z + (double)a.w*a.w;
#pragma unroll
    for (int m=1;m<64;m<<=1) sS += dshfl_xor(sS, m);
    double inv = 1.0/(sqrt(sS) + 1e-8);
    if (lane == 0){
        if (isLab) invL64[row] = inv;
        else invU64[row-LROWS] = inv;
    }
    float sc = (float)inv;
    ushort4 o;
    o.x = f2bf(a.x*sc); o.y = f2bf(a.y*sc); o.z = f2bf(a.z*sc); o.w = f2bf(a.w*sc);
    ushort_t* dst = isLab ? (labN + (size_t)row*D_CNT) : (unlN + (size_t)(row-LROWS)*D_CNT);
    *(ushort4*)&dst[lane*4] = o;
}

// -------- K2: bf16 MFMA modality GEMM -> 3 fp16 planes + fused chunk maxima --------
// grid (16, 157); block 256 (4 waves 2x2, wave tile 64x64). One dispatch for all u.
// R8-proven structure. Chunk maxima via monotone-max (R13-proven): fmaxf in f32,
// ONE f2key at the end (both transforms monotone) -> identical chunkMax bits.
__global__ __launch_bounds__(256, 2) void sim_kernel(
    const ushort_t* __restrict__ labN, const ushort_t* __restrict__ unlN,
    const float* __restrict__ w32, ushort_t* __restrict__ slabp,
    ushort_t* __restrict__ chunkMax)
{
    __shared__ ushort_t sA[128][64];   // 16 KB
    __shared__ ushort_t sB[128][64];   // 16 KB
    __shared__ float    sT[64][132];   // 33.8 KB (half-tile transpose, 2 phases)

    const int tid  = threadIdx.x;
    const int lane = tid & 63;
    const int w    = tid >> 6;
    const int wu = w >> 1, wl = w & 1;
    const int fr = lane & 15, fg = lane >> 4;

    const int uB = blockIdx.x * 128;
    const int l0 = blockIdx.y * 128;

    // staging: pre-swizzled global source, linear LDS dest (wave-uniform base)
    const int sr   = lane >> 3;                  // 0..7 sub-row within 8-row group
    const int scol = ((lane & 7) ^ sr) * 8;      // swizzled source col (elements)
    const ushort_t* pA[4]; const ushort_t* pB[4];
    ushort_t* dA[4]; ushort_t* dB[4];
#pragma unroll
    for (int g=0; g<4; g++){
        int ar = uB + g*32 + w*8 + sr;
        pA[g] = unlN + (size_t)ar*KTOT + scol;
        dA[g] = &sA[g*32 + w*8][0];
        int br = l0 + g*32 + w*8 + sr; if (br > L_CNT-1) br = L_CNT-1;
        pB[g] = labN + (size_t)br*KTOT + scol;
        dB[g] = &sB[g*32 + w*8][0];
    }

    // fragment read byte-offsets (matching XOR swizzle: slot ^= row&7)
    int aoff[4][2], boff[4][2];
#pragma unroll
    for (int i=0;i<4;i++)
#pragma unroll
        for (int ks=0;ks<2;ks++){
            int sw = ((ks*4 + fg) ^ (fr & 7)) * 16;
            aoff[i][ks] = (wu*64 + i*16 + fr)*128 + sw;
            boff[i][ks] = (wl*64 + i*16 + fr)*128 + sw;
        }

    // fp16-bit carry of this thread's 64 epilogue elements, for m=0 and m=1
    uint4 hA[2][4], hB[2][4];

#pragma unroll
    for (int m=0; m<M_CNT; m++){
        f32x4 acc[4][4];
#pragma unroll
        for (int i=0;i<4;i++)
#pragma unroll
            for (int j=0;j<4;j++) acc[i][j] = (f32x4){0.f,0.f,0.f,0.f};

#pragma unroll
        for (int kb=0; kb<4; kb++){
            const int koff = (m*4 + kb) * 64;
            __syncthreads();
#pragma unroll
            for (int g=0; g<4; g++){
                gload16(pA[g] + koff, dA[g]);
                gload16(pB[g] + koff, dB[g]);
            }
            __syncthreads();
#pragma unroll
            for (int ks=0; ks<2; ks++){
                bf16x8 af[4], bf[4];
#pragma unroll
                for (int i=0;i<4;i++) af[i] = *(const bf16x8*)((const char*)sA + aoff[i][ks]);
#pragma unroll
                for (int j=0;j<4;j++) bf[j] = *(const bf16x8*)((const char*)sB + boff[j][ks]);
#pragma unroll
                for (int i=0;i<4;i++)
#pragma unroll
                    for (int j=0;j<4;j++)
                        acc[i][j] = __builtin_amdgcn_mfma_f32_16x16x32_bf16(af[i], bf[j], acc[i][j], 0, 0, 0);
            }
        }

        // weights only needed for the fused maxima at m==2
        float wl5[T_CNT][3];
        if (m == 2){
#pragma unroll
            for (int t=0;t<T_CNT;t++)
#pragma unroll
                for (int j=0;j<3;j++) wl5[t][j] = w32[t*3+j];
        }

        // epilogue modality m: two-phase transpose (u-halves) through sT[64][132]
#pragma unroll
        for (int half=0; half<2; half++){
            __syncthreads();          // sT free (prev phase's reads done)
            if (wu == half){
#pragma unroll
                for (int i=0;i<4;i++)
#pragma unroll
                    for (int j=0;j<4;j++)
#pragma unroll
                        for (int r=0;r<4;r++)
                            sT[i*16 + fg*4 + r][wl*64 + j*16 + fr] = acc[i][j][r];
            }
            __syncthreads();
            // store 64 rows x 128 cols as fp16 (coalesced 16B per thread)
            const int c0 = (tid & 15) * 8;          // 0..120
#pragma unroll
            for (int it=0; it<4; it++){
                int row = it*16 + (tid >> 4);       // 0..63
                ushort_t h[8];
#pragma unroll
                for (int e=0;e<8;e++) h[e] = f2h(sT[row][c0 + e]);
                uint4 hv = *(const uint4*)h;
                size_t base = ((size_t)(uB + half*64 + row)*M_CNT + m)*LP + l0 + c0;
                *(uint4*)&slabp[base] = hv;

                if (m == 0) hA[half][it] = hv;
                else if (m == 1) hB[half][it] = hv;
                else {
                    // fused chunk maxima in FLOAT space (monotone-max), key-convert once
                    float rmf[T_CNT];
#pragma unroll
                    for (int t=0;t<T_CNT;t++) rmf[t] = -INFINITY;
#pragma unroll
                    for (int e=0;e<8;e++){
                        int l = l0 + c0 + e;
                        float a = h2f(get16(hA[half][it], e));
                        float b = h2f(get16(hB[half][it], e));
                        float c = h2f(get16(hv, e));
                        if (l < L_CNT){
#pragma unroll
                            for (int t=0;t<T_CNT;t++)
                                rmf[t] = fmaxf(rmf[t], comb3(wl5[t][0],wl5[t][1],wl5[t][2], a,b,c));
                        }
                    }
#pragma unroll
                    for (int t=0;t<T_CNT;t++){
                        float k = rmf[t];
                        k = fmaxf(k, __shfl_xor(k, 1, 64));
                        k = fmaxf(k, __shfl_xor(k, 2, 64));
                        k = fmaxf(k, __shfl_xor(k, 4, 64));
                        rmf[t] = k;
                    }
                    if ((tid & 7) == 0){
                        int chunkc = (l0 >> 6) + ((tid >> 3) & 1);
                        if (chunkc < CHUNKS){
                            int ug = uB + half*64 + row;
#pragma unroll
                            for (int t=0;t<T_CNT;t++)
                                chunkMax[((size_t)ug*T_CNT + t)*CPAD + chunkc] = f2key(rmf[t]);
                        }
                    }
                }
            }
        }
        __syncthreads();
    }
}

// -------- K3b: exact top-KC per (u,t) via chunk-pruned radix --------
// grid (U_CNT, T_CNT); block 256; ~8 KB LDS -> full occupancy.
__global__ __launch_bounds__(256) void select2_kernel(
    const ushort_t* __restrict__ slabp, const ushort_t* __restrict__ chunkMax,
    const float* __restrict__ w32, int* __restrict__ candIdx)
{
    __shared__ ushort_t mxs[CPAD];
    __shared__ ushort_t cand[CPAD];
    __shared__ uint_t hist[4][256];
    __shared__ uint_t h1[256], h2[256];
    __shared__ uint_t shB, shAbove, shNc, shCtr0, shCtr1;
    __shared__ int bufc[KC];

    const int tid = threadIdx.x, wid = tid >> 6;
    const int u = blockIdx.x, t = blockIdx.y;
    const float w0 = w32[t*3+0], w1 = w32[t*3+1], w2 = w32[t*3+2];
    const ushort_t* s0 = slabp + ((size_t)u*M_CNT + 0)*LP;
    const ushort_t* s1 = slabp + ((size_t)u*M_CNT + 1)*LP;
    const ushort_t* s2 = slabp + ((size_t)u*M_CNT + 2)*LP;
    const ushort_t* cm = chunkMax + ((size_t)u*T_CNT + t)*CPAD;

    for (int i=tid; i<CPAD; i+=256) mxs[i] = (i < CHUNKS) ? cm[i] : (ushort_t)0;
    hist[0][tid]=0; hist[1][tid]=0; hist[2][tid]=0; hist[3][tid]=0;
    if (tid == 0){ shNc = 0; shCtr0 = 0; shCtr1 = 0; }
    __syncthreads();

    // ---- tau = exact 16th-largest chunk max (2-level radix on 313 values) ----
    for (int i=tid; i<CHUNKS; i+=256) atomicAdd(&hist[wid][mxs[i] >> 8], 1u);
    __syncthreads();
    radix_find(hist, h1, h2, tid, 0u, KC, &shB, &shAbove);
    const uint_t MB = shB, mAb = shAbove;
    hist[0][tid]=0; hist[1][tid]=0; hist[2][tid]=0; hist[3][tid]=0;
    __syncthreads();
    for (int i=tid; i<CHUNKS; i+=256){
        uint_t k = mxs[i];
        if ((k >> 8) == MB) atomicAdd(&hist[wid][k & 0xFFu], 1u);
    }
    __syncthreads();
    radix_find(hist, h1, h2, tid, mAb, KC, &shB, &shAbove);
    const uint_t tau = (MB << 8) | shB;
    hist[0][tid]=0; hist[1][tid]=0; hist[2][tid]=0; hist[3][tid]=0;
    __syncthreads();

    // ---- collect candidate chunks ----
    for (int i=tid; i<CHUNKS; i+=256)
        if ((uint_t)mxs[i] >= tau) cand[atomicAdd(&shNc, 1u)] = (ushort_t)i;
    __syncthreads();
    const int NE = (int)shNc * 64;

    // ---- element pass 1: hi-byte histogram over candidate elements ----
    for (int j=tid; j<NE; j+=256){
        int l = (int)cand[j>>6]*64 + (j & 63);
        if (l < L_CNT){
            uint_t k = f2key(comb3(w0,w1,w2, h2f(s0[l]), h2f(s1[l]), h2f(s2[l])));
            atomicAdd(&hist[wid][k >> 8], 1u);
        }
    }
    __syncthreads();
    radix_find(hist, h1, h2, tid, 0u, KC, &shB, &shAbove);
    const uint_t EB = shB, eAb = shAbove;
    hist[0][tid]=0; hist[1][tid]=0; hist[2][tid]=0; hist[3][tid]=0;
    __syncthreads();

    // ---- element pass 2: low-byte within bucket EB ----
    for (int j=tid; j<NE; j+=256){
        int l = (int)cand[j>>6]*64 + (j & 63);
        if (l < L_CNT){
            uint_t k = f2key(comb3(w0,w1,w2, h2f(s0[l]), h2f(s1[l]), h2f(s2[l])));
            if ((k >> 8) == EB) atomicAdd(&hist[wid][k & 0xFFu], 1u);
        }
    }
    __syncthreads();
    radix_find(hist, h1, h2, tid, eAb, KC, &shB, &shAbove);
    const uint_t K16 = (EB << 8) | shB;
    const uint_t tot = shAbove;          // #(key > K16) < KC

    // ---- element pass 3: collect above-set + fill with ties ----
    for (int j=tid; j<NE; j+=256){
        int l = (int)cand[j>>6]*64 + (j & 63);
        if (l < L_CNT){
            uint_t k = f2key(comb3(w0,w1,w2, h2f(s0[l]), h2f(s1[l]), h2f(s2[l])));
            if (k > K16){
                bufc[atomicAdd(&shCtr0, 1u)] = l;
            } else if (k == K16){
                uint_t s = atomicAdd(&shCtr1, 1u) + tot;
                if (s < (uint_t)KC) bufc[s] = l;
            }
        }
    }
    __syncthreads();
    if (tid < KC) candIdx[((size_t)u*T_CNT + t)*KC + tid] = bufc[tid];
}

// -------- K4: f64 rescore, one wave per (u,t,candidate); single butterfly --------
__global__ __launch_bounds__(256) void rescore_kernel(
    const float* __restrict__ lab, const float* __restrict__ unl,
    const double* __restrict__ w64, const double* __restrict__ invL64,
    const double* __restrict__ invU64, const int* __restrict__ candIdx,
    double* __restrict__ candSim)
{
    int q = blockIdx.x*4 + (threadIdx.x >> 6);      // 0 .. U*T*KC-1
    int lane = threadIdx.x & 63;
    int ut = q >> 4;                                 // u*T + t
    int t = ut % T_CNT;
    int u = ut / T_CNT;
    int idx = candIdx[q];
    double p = 0.0;
#pragma unroll
    for (int m=0;m<M_CNT;m++){
        double s = w64[t*M_CNT+m] * invU64[u*M_CNT+m] * invL64[idx*M_CNT+m];
        float4 a = *(const float4*)&unl[(((size_t)u*M_CNT)+m)*D_CNT + lane*4];
        float4 b = *(const float4*)&lab[(((size_t)idx*M_CNT)+m)*D_CNT + lane*4];
        double d = (double)a.x*b.x + (double)a.y*b.y + (double)a.z*b.z + (double)a.w*b.w;
        p += s * d;
    }
#pragma unroll
    for (int mm=1;mm<64;mm<<=1) p += dshfl_xor(p, mm);
    if (lane == 0) candSim[q] = p;
}

// -------- K5: sort 16 candidates per (u,t), emit traits/index outputs --------
__global__ __launch_bounds__(256) void finalize_kernel(
    const double* __restrict__ candSim, const int* __restrict__ candIdx,
    const float* __restrict__ traits,
    float* __restrict__ outTraits, float* __restrict__ outIdx, int* __restrict__ finalIdx)
{
    int id = blockIdx.x*256 + threadIdx.x;
    if (id >= U_CNT*T_CNT) return;
    int t = id % T_CNT;
    double cv[KC]; int ci[KC];
#pragma unroll
    for (int c=0;c<KC;c++){ cv[c] = candSim[(size_t)id*KC + c]; ci[c] = candIdx[(size_t)id*KC + c]; }
#pragma unroll
    for (int i=0;i<KC;i++)
#pragma unroll
        for (int j=0;j<KC-1;j++){
            bool sw = (cv[j] < cv[j+1]) || (cv[j] == cv[j+1] && ci[j] > ci[j+1]);
            if (sw){ double tv=cv[j]; cv[j]=cv[j+1]; cv[j+1]=tv; int ti=ci[j]; ci[j]=ci[j+1]; ci[j+1]=ti; }
        }
#pragma unroll
    for (int k=0;k<K_OUT;k++){
        size_t ob = (size_t)id*K_OUT + k;
        int fi = ci[k];
        outTraits[ob] = traits[(size_t)fi*T_CNT + t];
        outIdx[ob] = (float)fi;
        finalIdx[ob] = fi;
    }
}

// -------- K6: embedding gather --------
__global__ __launch_bounds__(192) void gather_kernel(const float* __restrict__ lab,
    const int* __restrict__ finalIdx, float* __restrict__ outEmb)
{
    int b = blockIdx.x;
    int idx = finalIdx[b];
    const float4* src = (const float4*)(lab + (size_t)idx * (M_CNT*D_CNT));
    float4* dst = (float4*)(outEmb + (size_t)b * (M_CNT*D_CNT));
    dst[threadIdx.x] = src[threadIdx.x];
}

extern "C" void kernel_launch(void* const* d_in, const int* in_sizes, int n_in,
                              void* d_out, int out_size, void* d_ws, size_t ws_size,
                              hipStream_t stream) {
    const float* lab    = (const float*)d_in[0];   // [20000,3,256]
    const float* traits = (const float*)d_in[1];   // [20000,5]
    const float* unl    = (const float*)d_in[2];   // [2048,3,256]
    const float* logits = (const float*)d_in[3];   // [5,3]

    float* out = (float*)d_out;
    float* outEmb = out;                                           // U*T*K*M*D = 62,914,560 f32
    float* outTr  = out + (size_t)U_CNT*T_CNT*K_OUT*M_CNT*D_CNT;
    float* outIx  = outTr + (size_t)U_CNT*T_CNT*K_OUT;

    char* wsb = (char*)d_ws;
    size_t off = 0;
    auto take = [&](size_t bytes)->void*{
        void* p = wsb + off;
        off = (off + bytes + 255) & ~(size_t)255;
        return p;
    };
    double* invL64 = (double*)take((size_t)LROWS*sizeof(double));
    double* invU64 = (double*)take((size_t)UROWS*sizeof(double));
    float*  w32    = (float*) take(T_CNT*M_CNT*sizeof(float));
    double* w64    = (double*)take(T_CNT*M_CNT*sizeof(double));
    int*    candIdx= (int*)   take((size_t)U_CNT*T_CNT*KC*sizeof(int));
    double* candSim= (double*)take((size_t)U_CNT*T_CNT*KC*sizeof(double));
    int*    finalIdx=(int*)   take((size_t)U_CNT*T_CNT*K_OUT*sizeof(int));
    ushort_t* labN = (ushort_t*)take((size_t)LROWS*D_CNT*sizeof(ushort_t)); // 30.7 MB
    ushort_t* unlN = (ushort_t*)take((size_t)UROWS*D_CNT*sizeof(ushort_t)); // 3.15 MB
    ushort_t* chunkMax = (ushort_t*)take((size_t)U_CNT*T_CNT*CPAD*sizeof(ushort_t)); // 6.55 MB

    // modality-sim slab [u][m][LP] fp16 lives in d_out's embedding region:
    // 2048*3*20096*2 = 246.9 MB <= 251.66 MB. Fully consumed before gather.
    ushort_t* slabV = (ushort_t*)outEmb;

    {
        int nrow = LROWS + UROWS;
        prep_kernel<<<(nrow+3)/4, 256, 0, stream>>>(lab, unl, logits, invL64, invU64, labN, unlN, w32, w64);
    }
    sim_kernel<<<dim3(U_CNT/128, (L_CNT + 127)/128), 256, 0, stream>>>(labN, unlN, w32, slabV, chunkMax);
    select2_kernel<<<dim3(U_CNT, T_CNT), 256, 0, stream>>>(slabV, chunkMax, w32, candIdx);
    rescore_kernel<<<(U_CNT*T_CNT*KC)/4, 256, 0, stream>>>(lab, unl, w64, invL64, invU64, candIdx, candSim);
    finalize_kernel<<<(U_CNT*T_CNT + 255)/256, 256, 0, stream>>>(candSim, candIdx, traits, outTr, outIx, finalIdx);
    gather_kernel<<<U_CNT*T_CNT*K_OUT, 192, 0, stream>>>(lab, finalIdx, outEmb);
}

// Round 18
// 396.252 us; speedup vs baseline: 1.4060x; 1.0093x over previous
//
#include <hip/hip_runtime.h>
#include <hip/hip_bf16.h>
#include <math.h>

#define L_CNT 20000
#define U_CNT 2048
#define M_CNT 3
#define D_CNT 256
#define KTOT  768
#define T_CNT 5
#define K_OUT 8
#define KC    16
#define LP    20096              // 157*128, padded fp16 row stride
#define LROWS (L_CNT*M_CNT)      // 60000
#define UROWS (U_CNT*M_CNT)      // 6144
#define CHUNKS 313               // ceil(20000/64); chunk 312 has 32 valid elems
#define CPAD   320

typedef unsigned short ushort_t;
typedef unsigned int uint_t;
typedef __attribute__((ext_vector_type(8))) short bf16x8;
typedef __attribute__((ext_vector_type(4))) float f32x4;

// -------- helpers --------
__device__ inline double dshfl_xor(double v, int m){
    long long x = __double_as_longlong(v);
    int lo = (int)(x & 0xffffffffLL);
    int hi = (int)(((unsigned long long)x) >> 32);
    lo = __shfl_xor(lo, m, 64);
    hi = __shfl_xor(hi, m, 64);
    return __longlong_as_double(((long long)hi << 32) | (long long)(unsigned int)lo);
}
__device__ inline unsigned short f2bf(float f){
    unsigned int u = __float_as_uint(f);
    u = (u + 0x7fffu + ((u >> 16) & 1u)) >> 16;
    return (unsigned short)u;
}
__device__ __forceinline__ void gload16(const void* g, void* l){
    __builtin_amdgcn_global_load_lds(
        (const __attribute__((address_space(1))) unsigned int*)g,
        (__attribute__((address_space(3))) unsigned int*)l, 16, 0, 0);
}
__device__ __forceinline__ float h2f(ushort_t h){
    _Float16 x; __builtin_memcpy(&x, &h, 2); return (float)x;
}
// f32 -> fp16 bits (RNE)
__device__ __forceinline__ ushort_t f2h(float f){
    _Float16 hv = (_Float16)f;
    ushort_t b; __builtin_memcpy(&b, &hv, 2);
    return b;
}
// f32 -> fp16 bits -> sortable u16 key (unsigned compare == float compare)
__device__ __forceinline__ ushort_t f2key(float f){
    ushort_t b = f2h(f);
    ushort_t mask = (ushort_t)(0x8000u | (((short)b >> 15) & 0x7FFF));
    return (ushort_t)(b ^ mask);
}
__device__ __forceinline__ ushort_t get16(const uint4& v, int e){
    uint_t w = (e < 2) ? v.x : (e < 4) ? v.y : (e < 6) ? v.z : v.w;
    return (ushort_t)((e & 1) ? (w >> 16) : (w & 0xFFFFu));
}
// fixed-order combine: MUST be bit-identical everywhere it is evaluated
__device__ __forceinline__ float comb3(float w0, float w1, float w2, float a, float b, float c){
    return fmaf(w2, c, fmaf(w1, b, w0*a));
}
// suffix-scan a 256-bucket histogram, find bucket where count(>=) crosses kc
__device__ __forceinline__ void radix_find(uint_t hist[4][256], uint_t* h1, uint_t* h2,
    int tid, uint_t addBase, uint_t kc, uint_t* shB, uint_t* shAbove)
{
    h1[tid] = hist[0][tid]+hist[1][tid]+hist[2][tid]+hist[3][tid];
    uint_t* src = h1; uint_t* dst = h2;
    for (int st=1; st<256; st<<=1){
        __syncthreads();
        dst[tid] = src[tid] + ((tid+st < 256) ? src[tid+st] : 0u);
        uint_t* tt = src; src = dst; dst = tt;
    }
    __syncthreads();
    uint_t ge = src[tid] + addBase;
    uint_t gt = ((tid < 255) ? src[tid+1] : 0u) + addBase;
    if (ge >= kc && gt < kc){ *shB = (uint_t)tid; *shAbove = gt; }
    __syncthreads();
}

// -------- K1: f64 inv-norms + normalized bf16 copies + softmax weights (fused) --------
__global__ __launch_bounds__(256) void prep_kernel(const float* __restrict__ lab,
    const float* __restrict__ unl, const float* __restrict__ logits,
    double* __restrict__ invL64, double* __restrict__ invU64,
    ushort_t* __restrict__ labN, ushort_t* __restrict__ unlN,
    float* __restrict__ w32, double* __restrict__ w64){
    // block 0 additionally computes the softmax weights (tiny)
    if (blockIdx.x == 0 && threadIdx.x < T_CNT){
        int t = threadIdx.x;
        float a = logits[t*M_CNT+0], b = logits[t*M_CNT+1], c = logits[t*M_CNT+2];
        float mx = fmaxf(a, fmaxf(b, c));
        float e0 = expf(a-mx), e1 = expf(b-mx), e2 = expf(c-mx);
        float s = e0+e1+e2;
        w32[t*M_CNT+0] = e0/s; w32[t*M_CNT+1] = e1/s; w32[t*M_CNT+2] = e2/s;
        double da=(double)a, db=(double)b, dc=(double)c;
        double dmx = fmax(da, fmax(db, dc));
        double f0 = exp(da-dmx), f1 = exp(db-dmx), f2 = exp(dc-dmx);
        double ds = f0+f1+f2;
        w64[t*M_CNT+0] = f0/ds; w64[t*M_CNT+1] = f1/ds; w64[t*M_CNT+2] = f2/ds;
    }
    const int NROW = LROWS + UROWS;
    int row = blockIdx.x*4 + (threadIdx.x >> 6);
    int lane = threadIdx.x & 63;
    if (row >= NROW) return;
    bool isLab = row < LROWS;
    const float* p = isLab ? (lab + (size_t)row*D_CNT) : (unl + (size_t)(row-LROWS)*D_CNT);
    float4 a = ((const float4*)p)[lane];
    double sS = (double)a.x*a.x + (double)a.y*a.y + (double)a.z*a.z + (double)a.w*a.w;
#pragma unroll
    for (int m=1;m<64;m<<=1) sS += dshfl_xor(sS, m);
    double inv = 1.0/(sqrt(sS) + 1e-8);
    if (lane == 0){
        if (isLab) invL64[row] = inv;
        else invU64[row-LROWS] = inv;
    }
    float sc = (float)inv;
    ushort4 o;
    o.x = f2bf(a.x*sc); o.y = f2bf(a.y*sc); o.z = f2bf(a.z*sc); o.w = f2bf(a.w*sc);
    ushort_t* dst = isLab ? (labN + (size_t)row*D_CNT) : (unlN + (size_t)(row-LROWS)*D_CNT);
    *(ushort4*)&dst[lane*4] = o;
}

// -------- K2: bf16 MFMA modality GEMM -> 3 fp16 planes + fused chunk maxima --------
// grid (16, 157); block 256 (4 waves 2x2, wave tile 64x64). One dispatch for all u.
// SINGLE-PHASE fp16 transpose epilogue: sT[128][136] holds the full tile as fp16
// (write-side f2h = same RNE bits as read-side convert), 1 barrier per epilogue
// instead of 5, no divergent half-phases. Chunk maxima via monotone-max (R13).
__global__ __launch_bounds__(256, 2) void sim_kernel(
    const ushort_t* __restrict__ labN, const ushort_t* __restrict__ unlN,
    const float* __restrict__ w32, ushort_t* __restrict__ slabp,
    ushort_t* __restrict__ chunkMax)
{
    __shared__ ushort_t sA[128][64];   // 16 KB
    __shared__ ushort_t sB[128][64];   // 16 KB
    __shared__ ushort_t sT[128][136];  // 34 KB (fp16 full-tile transpose)

    const int tid  = threadIdx.x;
    const int lane = tid & 63;
    const int w    = tid >> 6;
    const int wu = w >> 1, wl = w & 1;
    const int fr = lane & 15, fg = lane >> 4;

    const int uB = blockIdx.x * 128;
    const int l0 = blockIdx.y * 128;

    // staging: pre-swizzled global source, linear LDS dest (wave-uniform base)
    const int sr   = lane >> 3;                  // 0..7 sub-row within 8-row group
    const int scol = ((lane & 7) ^ sr) * 8;      // swizzled source col (elements)
    const ushort_t* pA[4]; const ushort_t* pB[4];
    ushort_t* dA[4]; ushort_t* dB[4];
#pragma unroll
    for (int g=0; g<4; g++){
        int ar = uB + g*32 + w*8 + sr;
        pA[g] = unlN + (size_t)ar*KTOT + scol;
        dA[g] = &sA[g*32 + w*8][0];
        int br = l0 + g*32 + w*8 + sr; if (br > L_CNT-1) br = L_CNT-1;
        pB[g] = labN + (size_t)br*KTOT + scol;
        dB[g] = &sB[g*32 + w*8][0];
    }

    // fragment read byte-offsets (matching XOR swizzle: slot ^= row&7)
    int aoff[4][2], boff[4][2];
#pragma unroll
    for (int i=0;i<4;i++)
#pragma unroll
        for (int ks=0;ks<2;ks++){
            int sw = ((ks*4 + fg) ^ (fr & 7)) * 16;
            aoff[i][ks] = (wu*64 + i*16 + fr)*128 + sw;
            boff[i][ks] = (wl*64 + i*16 + fr)*128 + sw;
        }

    // fp16-bit carry of this thread's 128 epilogue elements, for m=0 and m=1
    uint4 hA[8], hB[8];

#pragma unroll
    for (int m=0; m<M_CNT; m++){
        f32x4 acc[4][4];
#pragma unroll
        for (int i=0;i<4;i++)
#pragma unroll
            for (int j=0;j<4;j++) acc[i][j] = (f32x4){0.f,0.f,0.f,0.f};

#pragma unroll
        for (int kb=0; kb<4; kb++){
            const int koff = (m*4 + kb) * 64;
            __syncthreads();
#pragma unroll
            for (int g=0; g<4; g++){
                gload16(pA[g] + koff, dA[g]);
                gload16(pB[g] + koff, dB[g]);
            }
            __syncthreads();
#pragma unroll
            for (int ks=0; ks<2; ks++){
                bf16x8 af[4], bf[4];
#pragma unroll
                for (int i=0;i<4;i++) af[i] = *(const bf16x8*)((const char*)sA + aoff[i][ks]);
#pragma unroll
                for (int j=0;j<4;j++) bf[j] = *(const bf16x8*)((const char*)sB + boff[j][ks]);
#pragma unroll
                for (int i=0;i<4;i++)
#pragma unroll
                    for (int j=0;j<4;j++)
                        acc[i][j] = __builtin_amdgcn_mfma_f32_16x16x32_bf16(af[i], bf[j], acc[i][j], 0, 0, 0);
            }
        }

        // weights only needed for the fused maxima at m==2
        float wl5[T_CNT][3];
        if (m == 2){
#pragma unroll
            for (int t=0;t<T_CNT;t++)
#pragma unroll
                for (int j=0;j<3;j++) wl5[t][j] = w32[t*3+j];
        }

        // ---- single-phase epilogue: all waves write fp16 transpose, one barrier ----
        // (prev m's sT reads are >=8 barriers back; sT/sA/sB disjoint -> no lead barrier)
#pragma unroll
        for (int i=0;i<4;i++)
#pragma unroll
            for (int j=0;j<4;j++)
#pragma unroll
                for (int r=0;r<4;r++)
                    sT[wu*64 + i*16 + fg*4 + r][wl*64 + j*16 + fr] = f2h(acc[i][j][r]);
        __syncthreads();
        // read + store 128 rows x 128 cols (coalesced 16B per thread)
        {
            const int c0 = (tid & 15) * 8;          // 0..120
#pragma unroll
            for (int it=0; it<8; it++){
                int row = it*16 + (tid >> 4);       // 0..127
                uint4 hv = *(const uint4*)&sT[row][c0];
                size_t base = ((size_t)(uB + row)*M_CNT + m)*LP + l0 + c0;
                *(uint4*)&slabp[base] = hv;

                if (m == 0) hA[it] = hv;
                else if (m == 1) hB[it] = hv;
                else {
                    // fused chunk maxima in FLOAT space (monotone-max), key-convert once
                    float rmf[T_CNT];
#pragma unroll
                    for (int t=0;t<T_CNT;t++) rmf[t] = -INFINITY;
#pragma unroll
                    for (int e=0;e<8;e++){
                        int l = l0 + c0 + e;
                        float a = h2f(get16(hA[it], e));
                        float b = h2f(get16(hB[it], e));
                        float c = h2f(get16(hv, e));
                        if (l < L_CNT){
#pragma unroll
                            for (int t=0;t<T_CNT;t++)
                                rmf[t] = fmaxf(rmf[t], comb3(wl5[t][0],wl5[t][1],wl5[t][2], a,b,c));
                        }
                    }
#pragma unroll
                    for (int t=0;t<T_CNT;t++){
                        float k = rmf[t];
                        k = fmaxf(k, __shfl_xor(k, 1, 64));
                        k = fmaxf(k, __shfl_xor(k, 2, 64));
                        k = fmaxf(k, __shfl_xor(k, 4, 64));
                        rmf[t] = k;
                    }
                    if ((tid & 7) == 0){
                        int chunkc = (l0 >> 6) + ((tid >> 3) & 1);
                        if (chunkc < CHUNKS){
                            int ug = uB + row;
#pragma unroll
                            for (int t=0;t<T_CNT;t++)
                                chunkMax[((size_t)ug*T_CNT + t)*CPAD + chunkc] = f2key(rmf[t]);
                        }
                    }
                }
            }
        }
    }
}

// -------- K3b: exact top-KC per (u,t) via chunk-pruned radix --------
// grid (U_CNT, T_CNT); block 256; ~8 KB LDS -> full occupancy.
__global__ __launch_bounds__(256) void select2_kernel(
    const ushort_t* __restrict__ slabp, const ushort_t* __restrict__ chunkMax,
    const float* __restrict__ w32, int* __restrict__ candIdx)
{
    __shared__ ushort_t mxs[CPAD];
    __shared__ ushort_t cand[CPAD];
    __shared__ uint_t hist[4][256];
    __shared__ uint_t h1[256], h2[256];
    __shared__ uint_t shB, shAbove, shNc, shCtr0, shCtr1;
    __shared__ int bufc[KC];

    const int tid = threadIdx.x, wid = tid >> 6;
    const int u = blockIdx.x, t = blockIdx.y;
    const float w0 = w32[t*3+0], w1 = w32[t*3+1], w2 = w32[t*3+2];
    const ushort_t* s0 = slabp + ((size_t)u*M_CNT + 0)*LP;
    const ushort_t* s1 = slabp + ((size_t)u*M_CNT + 1)*LP;
    const ushort_t* s2 = slabp + ((size_t)u*M_CNT + 2)*LP;
    const ushort_t* cm = chunkMax + ((size_t)u*T_CNT + t)*CPAD;

    for (int i=tid; i<CPAD; i+=256) mxs[i] = (i < CHUNKS) ? cm[i] : (ushort_t)0;
    hist[0][tid]=0; hist[1][tid]=0; hist[2][tid]=0; hist[3][tid]=0;
    if (tid == 0){ shNc = 0; shCtr0 = 0; shCtr1 = 0; }
    __syncthreads();

    // ---- tau = exact 16th-largest chunk max (2-level radix on 313 values) ----
    for (int i=tid; i<CHUNKS; i+=256) atomicAdd(&hist[wid][mxs[i] >> 8], 1u);
    __syncthreads();
    radix_find(hist, h1, h2, tid, 0u, KC, &shB, &shAbove);
    const uint_t MB = shB, mAb = shAbove;
    hist[0][tid]=0; hist[1][tid]=0; hist[2][tid]=0; hist[3][tid]=0;
    __syncthreads();
    for (int i=tid; i<CHUNKS; i+=256){
        uint_t k = mxs[i];
        if ((k >> 8) == MB) atomicAdd(&hist[wid][k & 0xFFu], 1u);
    }
    __syncthreads();
    radix_find(hist, h1, h2, tid, mAb, KC, &shB, &shAbove);
    const uint_t tau = (MB << 8) | shB;
    hist[0][tid]=0; hist[1][tid]=0; hist[2][tid]=0; hist[3][tid]=0;
    __syncthreads();

    // ---- collect candidate chunks ----
    for (int i=tid; i<CHUNKS; i+=256)
        if ((uint_t)mxs[i] >= tau) cand[atomicAdd(&shNc, 1u)] = (ushort_t)i;
    __syncthreads();
    const int NE = (int)shNc * 64;

    // ---- element pass 1: hi-byte histogram over candidate elements ----
    for (int j=tid; j<NE; j+=256){
        int l = (int)cand[j>>6]*64 + (j & 63);
        if (l < L_CNT){
            uint_t k = f2key(comb3(w0,w1,w2, h2f(s0[l]), h2f(s1[l]), h2f(s2[l])));
            atomicAdd(&hist[wid][k >> 8], 1u);
        }
    }
    __syncthreads();
    radix_find(hist, h1, h2, tid, 0u, KC, &shB, &shAbove);
    const uint_t EB = shB, eAb = shAbove;
    hist[0][tid]=0; hist[1][tid]=0; hist[2][tid]=0; hist[3][tid]=0;
    __syncthreads();

    // ---- element pass 2: low-byte within bucket EB ----
    for (int j=tid; j<NE; j+=256){
        int l = (int)cand[j>>6]*64 + (j & 63);
        if (l < L_CNT){
            uint_t k = f2key(comb3(w0,w1,w2, h2f(s0[l]), h2f(s1[l]), h2f(s2[l])));
            if ((k >> 8) == EB) atomicAdd(&hist[wid][k & 0xFFu], 1u);
        }
    }
    __syncthreads();
    radix_find(hist, h1, h2, tid, eAb, KC, &shB, &shAbove);
    const uint_t K16 = (EB << 8) | shB;
    const uint_t tot = shAbove;          // #(key > K16) < KC

    // ---- element pass 3: collect above-set + fill with ties ----
    for (int j=tid; j<NE; j+=256){
        int l = (int)cand[j>>6]*64 + (j & 63);
        if (l < L_CNT){
            uint_t k = f2key(comb3(w0,w1,w2, h2f(s0[l]), h2f(s1[l]), h2f(s2[l])));
            if (k > K16){
                bufc[atomicAdd(&shCtr0, 1u)] = l;
            } else if (k == K16){
                uint_t s = atomicAdd(&shCtr1, 1u) + tot;
                if (s < (uint_t)KC) bufc[s] = l;
            }
        }
    }
    __syncthreads();
    if (tid < KC) candIdx[((size_t)u*T_CNT + t)*KC + tid] = bufc[tid];
}

// -------- K4: f64 rescore, one wave per (u,t,candidate); single butterfly --------
__global__ __launch_bounds__(256) void rescore_kernel(
    const float* __restrict__ lab, const float* __restrict__ unl,
    const double* __restrict__ w64, const double* __restrict__ invL64,
    const double* __restrict__ invU64, const int* __restrict__ candIdx,
    double* __restrict__ candSim)
{
    int q = blockIdx.x*4 + (threadIdx.x >> 6);      // 0 .. U*T*KC-1
    int lane = threadIdx.x & 63;
    int ut = q >> 4;                                 // u*T + t
    int t = ut % T_CNT;
    int u = ut / T_CNT;
    int idx = candIdx[q];
    double p = 0.0;
#pragma unroll
    for (int m=0;m<M_CNT;m++){
        double s = w64[t*M_CNT+m] * invU64[u*M_CNT+m] * invL64[idx*M_CNT+m];
        float4 a = *(const float4*)&unl[(((size_t)u*M_CNT)+m)*D_CNT + lane*4];
        float4 b = *(const float4*)&lab[(((size_t)idx*M_CNT)+m)*D_CNT + lane*4];
        double d = (double)a.x*b.x + (double)a.y*b.y + (double)a.z*b.z + (double)a.w*b.w;
        p += s * d;
    }
#pragma unroll
    for (int mm=1;mm<64;mm<<=1) p += dshfl_xor(p, mm);
    if (lane == 0) candSim[q] = p;
}

// -------- K5: sort 16 candidates per (u,t), emit traits/index outputs --------
__global__ __launch_bounds__(256) void finalize_kernel(
    const double* __restrict__ candSim, const int* __restrict__ candIdx,
    const float* __restrict__ traits,
    float* __restrict__ outTraits, float* __restrict__ outIdx, int* __restrict__ finalIdx)
{
    int id = blockIdx.x*256 + threadIdx.x;
    if (id >= U_CNT*T_CNT) return;
    int t = id % T_CNT;
    double cv[KC]; int ci[KC];
#pragma unroll
    for (int c=0;c<KC;c++){ cv[c] = candSim[(size_t)id*KC + c]; ci[c] = candIdx[(size_t)id*KC + c]; }
#pragma unroll
    for (int i=0;i<KC;i++)
#pragma unroll
        for (int j=0;j<KC-1;j++){
            bool sw = (cv[j] < cv[j+1]) || (cv[j] == cv[j+1] && ci[j] > ci[j+1]);
            if (sw){ double tv=cv[j]; cv[j]=cv[j+1]; cv[j+1]=tv; int ti=ci[j]; ci[j]=ci[j+1]; ci[j+1]=ti; }
        }
#pragma unroll
    for (int k=0;k<K_OUT;k++){
        size_t ob = (size_t)id*K_OUT + k;
        int fi = ci[k];
        outTraits[ob] = traits[(size_t)fi*T_CNT + t];
        outIdx[ob] = (float)fi;
        finalIdx[ob] = fi;
    }
}

// -------- K6: embedding gather --------
__global__ __launch_bounds__(192) void gather_kernel(const float* __restrict__ lab,
    const int* __restrict__ finalIdx, float* __restrict__ outEmb)
{
    int b = blockIdx.x;
    int idx = finalIdx[b];
    const float4* src = (const float4*)(lab + (size_t)idx * (M_CNT*D_CNT));
    float4* dst = (float4*)(outEmb + (size_t)b * (M_CNT*D_CNT));
    dst[threadIdx.x] = src[threadIdx.x];
}

extern "C" void kernel_launch(void* const* d_in, const int* in_sizes, int n_in,
                              void* d_out, int out_size, void* d_ws, size_t ws_size,
                              hipStream_t stream) {
    const float* lab    = (const float*)d_in[0];   // [20000,3,256]
    const float* traits = (const float*)d_in[1];   // [20000,5]
    const float* unl    = (const float*)d_in[2];   // [2048,3,256]
    const float* logits = (const float*)d_in[3];   // [5,3]

    float* out = (float*)d_out;
    float* outEmb = out;                                           // U*T*K*M*D = 62,914,560 f32
    float* outTr  = out + (size_t)U_CNT*T_CNT*K_OUT*M_CNT*D_CNT;
    float* outIx  = outTr + (size_t)U_CNT*T_CNT*K_OUT;

    char* wsb = (char*)d_ws;
    size_t off = 0;
    auto take = [&](size_t bytes)->void*{
        void* p = wsb + off;
        off = (off + bytes + 255) & ~(size_t)255;
        return p;
    };
    double* invL64 = (double*)take((size_t)LROWS*sizeof(double));
    double* invU64 = (double*)take((size_t)UROWS*sizeof(double));
    float*  w32    = (float*) take(T_CNT*M_CNT*sizeof(float));
    double* w64    = (double*)take(T_CNT*M_CNT*sizeof(double));
    int*    candIdx= (int*)   take((size_t)U_CNT*T_CNT*KC*sizeof(int));
    double* candSim= (double*)take((size_t)U_CNT*T_CNT*KC*sizeof(double));
    int*    finalIdx=(int*)   take((size_t)U_CNT*T_CNT*K_OUT*sizeof(int));
    ushort_t* labN = (ushort_t*)take((size_t)LROWS*D_CNT*sizeof(ushort_t)); // 30.7 MB
    ushort_t* unlN = (ushort_t*)take((size_t)UROWS*D_CNT*sizeof(ushort_t)); // 3.15 MB
    ushort_t* chunkMax = (ushort_t*)take((size_t)U_CNT*T_CNT*CPAD*sizeof(ushort_t)); // 6.55 MB

    // modality-sim slab [u][m][LP] fp16 lives in d_out's embedding region:
    // 2048*3*20096*2 = 246.9 MB <= 251.66 MB. Fully consumed before gather.
    ushort_t* slabV = (ushort_t*)outEmb;

    {
        int nrow = LROWS + UROWS;
        prep_kernel<<<(nrow+3)/4, 256, 0, stream>>>(lab, unl, logits, invL64, invU64, labN, unlN, w32, w64);
    }
    sim_kernel<<<dim3(U_CNT/128, (L_CNT + 127)/128), 256, 0, stream>>>(labN, unlN, w32, slabV, chunkMax);
    select2_kernel<<<dim3(U_CNT, T_CNT), 256, 0, stream>>>(slabV, chunkMax, w32, candIdx);
    rescore_kernel<<<(U_CNT*T_CNT*KC)/4, 256, 0, stream>>>(lab, unl, w64, invL64, invU64, candIdx, candSim);
    finalize_kernel<<<(U_CNT*T_CNT + 255)/256, 256, 0, stream>>>(candSim, candIdx, traits, outTr, outIx, finalIdx);
    gather_kernel<<<U_CNT*T_CNT*K_OUT, 192, 0, stream>>>(lab, finalIdx, outEmb);
}